// Round 1
// 2026.027 us; speedup vs baseline: 1.1290x; 1.1290x over previous
//
#include <hip/hip_runtime.h>
#include <float.h>
#include <math.h>

#define D 1024
#define NF 64
#define MDICT 16384
#define NH 16
#define DH 64
#define TT 2048
#define ROWS 4096   // B*T
#define DFF 4096

// d_out layout (floats)
#define OUT_X     0LL
#define OUT_ATTN  4194304LL
#define OUT_FS    138412032LL
#define OUT_SPARS 138674176LL
#define OUT_E1    138674177LL
#define OUT_E2    138674178LL

typedef __attribute__((ext_vector_type(8))) short short8;
typedef __attribute__((ext_vector_type(4))) float f32x4;

__device__ inline unsigned short f2bf(float f) {
    unsigned int u = __float_as_uint(f);
    u = u + 0x7FFFu + ((u >> 16) & 1u);   // round-to-nearest-even (finite vals)
    return (unsigned short)(u >> 16);
}
__device__ inline float bf2f(unsigned int s) {
    return __uint_as_float(s << 16);
}

// ---------------- block reduce helpers (blockDim == 256) ----------------
__device__ inline float blk_sum(float v) {
    __shared__ float sb[4];
    int lane = threadIdx.x & 63, w = threadIdx.x >> 6;
#pragma unroll
    for (int o = 32; o; o >>= 1) v += __shfl_down(v, o);
    if (lane == 0) sb[w] = v;
    __syncthreads();
    float s = sb[0] + sb[1] + sb[2] + sb[3];
    __syncthreads();
    return s;
}

// =======================================================================
// bf16 MFMA GEMM: C = alpha * A @ B^T (+ addC).  A:[M,K] B:[N,K] row-major.
// BK=32, 256 threads = 4 waves in 2x2; wave tile (BM/2)x(BN/2) of 16x16x32
// MFMAs. B staged via global_load_lds (16B); A likewise unless ACONV, in
// which case A is fp32 in global and is converted in VGPRs + ds_write_b128.
// Grid: (N/BN, M/BM, batches); z -> zo=z/batchH, zi=z%batchH.
// =======================================================================
template<int BM, int BN, bool OBF, bool ACONV>
__global__ __launch_bounds__(256) void gemm_mfma(
    const void* __restrict__ Abv, const unsigned short* __restrict__ Bb,
    void* __restrict__ Cbv, const float* __restrict__ addCb,
    int K, int lda, int ldb, int ldc, float alpha, int batchH,
    long long aOut, long long aIn, long long bOut, long long bIn,
    long long cOut, long long cIn)
{
    int z = blockIdx.z;
    int zo = z / batchH, zi = z - zo * batchH;
    long long aoff = zo * aOut + zi * aIn;
    const unsigned short* B = Bb + zo * bOut + zi * bIn;
    long long cbase = zo * cOut + zi * cIn;
    const float* addC = addCb ? (addCb + cbase) : nullptr;

    __shared__ __align__(16) unsigned short As[BM * 32];
    __shared__ __align__(16) unsigned short Bs[BN * 32];

    int tid = threadIdx.x;
    int lane = tid & 63, wave = tid >> 6;
    int wr = wave >> 1, wc = wave & 1;
    long long r0 = (long long)blockIdx.y * BM;
    long long c0 = (long long)blockIdx.x * BN;

    constexpr int TI = BM / 32;   // row tiles per wave
    constexpr int TJ = BN / 32;   // col tiles per wave
    constexpr int RA = BM * 4 / 256;
    constexpr int RB = BN * 4 / 256;

    f32x4 acc[TI][TJ] = {};
    int lm = lane & 15;
    int kq = (lane >> 4) * 8;

    for (int k0 = 0; k0 < K; k0 += 32) {
        __syncthreads();
        // ---- stage B (bf16, global->LDS direct) ----
#pragma unroll
        for (int r = 0; r < RB; r++) {
            int q = r * 256 + tid;
            const unsigned short* gp = B + (c0 + (q >> 2)) * (long long)ldb + k0 + (q & 3) * 8;
            unsigned short* lp = Bs + (r * 256 + (tid & 192)) * 8;  // wave-uniform base
            __builtin_amdgcn_global_load_lds(
                (const __attribute__((address_space(1))) void*)gp,
                (__attribute__((address_space(3))) void*)lp, 16, 0, 0);
        }
        // ---- stage A ----
        if (ACONV) {
            const float* A = (const float*)Abv + aoff;
#pragma unroll
            for (int r = 0; r < RA; r++) {
                int q = r * 256 + tid;
                const float* gp = A + (r0 + (q >> 2)) * (long long)lda + k0 + (q & 3) * 8;
                float4 v0 = *(const float4*)gp;
                float4 v1 = *(const float4*)(gp + 4);
                short8 f;
                f[0] = (short)f2bf(v0.x); f[1] = (short)f2bf(v0.y);
                f[2] = (short)f2bf(v0.z); f[3] = (short)f2bf(v0.w);
                f[4] = (short)f2bf(v1.x); f[5] = (short)f2bf(v1.y);
                f[6] = (short)f2bf(v1.z); f[7] = (short)f2bf(v1.w);
                *(short8*)&As[q * 8] = f;
            }
        } else {
            const unsigned short* A = (const unsigned short*)Abv + aoff;
#pragma unroll
            for (int r = 0; r < RA; r++) {
                int q = r * 256 + tid;
                const unsigned short* gp = A + (r0 + (q >> 2)) * (long long)lda + k0 + (q & 3) * 8;
                unsigned short* lp = As + (r * 256 + (tid & 192)) * 8;
                __builtin_amdgcn_global_load_lds(
                    (const __attribute__((address_space(1))) void*)gp,
                    (__attribute__((address_space(3))) void*)lp, 16, 0, 0);
            }
        }
        __syncthreads();
        // ---- fragments + MFMA ----
        short8 af[TI], bfr[TJ];
#pragma unroll
        for (int i = 0; i < TI; i++)
            af[i] = *(const short8*)&As[(wr * (BM / 2) + i * 16 + lm) * 32 + kq];
#pragma unroll
        for (int j = 0; j < TJ; j++)
            bfr[j] = *(const short8*)&Bs[(wc * (BN / 2) + j * 16 + lm) * 32 + kq];
#pragma unroll
        for (int i = 0; i < TI; i++)
#pragma unroll
            for (int j = 0; j < TJ; j++)
                acc[i][j] = __builtin_amdgcn_mfma_f32_16x16x32_bf16(af[i], bfr[j], acc[i][j], 0, 0, 0);
    }

    // ---- epilogue: C/D layout col=lane&15, row=(lane>>4)*4+reg ----
#pragma unroll
    for (int i = 0; i < TI; i++) {
#pragma unroll
        for (int r = 0; r < 4; r++) {
            long long row = r0 + wr * (BM / 2) + i * 16 + (lane >> 4) * 4 + r;
#pragma unroll
            for (int j = 0; j < TJ; j++) {
                long long col = c0 + wc * (BN / 2) + j * 16 + lm;
                long long idx = row * (long long)ldc + col;
                float v = alpha * acc[i][j][r];
                if (addC) v += addC[idx];
                if (OBF) ((unsigned short*)Cbv)[cbase + idx] = f2bf(v);
                else     ((float*)Cbv)[cbase + idx] = v;
            }
        }
    }
}

// ---------------- fp32 -> bf16 convert (grid-stride, 4/thread) -----------
__global__ __launch_bounds__(256) void cvt_bf16_kernel(
    const float* __restrict__ in, unsigned short* __restrict__ out, long long n4)
{
    long long i = (long long)blockIdx.x * 256 + threadIdx.x;
    long long stride = (long long)gridDim.x * 256;
    for (; i < n4; i += stride) {
        float4 v = ((const float4*)in)[i];
        uint2 p;
        p.x = (unsigned)f2bf(v.x) | ((unsigned)f2bf(v.y) << 16);
        p.y = (unsigned)f2bf(v.z) | ((unsigned)f2bf(v.w) << 16);
        ((uint2*)out)[i] = p;
    }
}

// ---------------- family gate: logits + softmax ----------------
__global__ __launch_bounds__(64) void family_kernel(
    const float* __restrict__ x, const float* __restrict__ fgw,
    float* __restrict__ fs_out)
{
    __shared__ float xs[D];
    int r = blockIdx.x, f = threadIdx.x;
    const float4* x4 = (const float4*)(x + (long long)r * D);
    float4* xs4 = (float4*)xs;
#pragma unroll
    for (int i = 0; i < 4; i++) xs4[f + 64 * i] = x4[f + 64 * i];
    __syncthreads();
    const float4* w4 = (const float4*)(fgw + (long long)f * D);
    float acc = 0.f;
#pragma unroll 8
    for (int d = 0; d < D / 4; d++) {
        float4 w = w4[d];
        float4 xv = xs4[d];
        acc += w.x * xv.x + w.y * xv.y + w.z * xv.z + w.w * xv.w;
    }
    float mx = acc;
#pragma unroll
    for (int o = 32; o; o >>= 1) mx = fmaxf(mx, __shfl_xor(mx, o));
    float e = __expf(acc - mx);
    float s = e;
#pragma unroll
    for (int o = 32; o; o >>= 1) s += __shfl_xor(s, o);
    fs_out[(long long)r * NF + f] = e / s;
}

// ------- basis = fs @ proto (fp32 out) ; resid = x - basis (bf16 out) ----
__global__ __launch_bounds__(256) void basis_kernel(
    const float* __restrict__ x, const float* __restrict__ fs,
    const float* __restrict__ proto, float* __restrict__ basis,
    unsigned short* __restrict__ resid_bf)
{
    __shared__ float Ss[NF];
    int r = blockIdx.x, tid = threadIdx.x;
    if (tid < NF) Ss[tid] = fs[(long long)r * NF + tid];
    __syncthreads();
    float4 acc = {0.f, 0.f, 0.f, 0.f};
    const float4* p4 = (const float4*)proto;
#pragma unroll 8
    for (int k = 0; k < NF; k++) {
        float s = Ss[k];
        float4 p = p4[k * (D / 4) + tid];
        acc.x += s * p.x; acc.y += s * p.y; acc.z += s * p.z; acc.w += s * p.w;
    }
    long long base = (long long)r * (D / 4) + tid;
    float4 xv = ((const float4*)x)[base];
    ((float4*)basis)[base] = acc;
    uint2 rp;
    rp.x = (unsigned)f2bf(xv.x - acc.x) | ((unsigned)f2bf(xv.y - acc.y) << 16);
    rp.y = (unsigned)f2bf(xv.z - acc.z) | ((unsigned)f2bf(xv.w - acc.w) << 16);
    ((uint2*)resid_bf)[base] = rp;
}

// ---------------- top-8 per row of coeffs [4096, 16384] ----------------
__device__ inline void ins8(float v, int idx, float* vs, int* is) {
    if (v <= vs[7]) return;
    vs[7] = v; is[7] = idx;
#pragma unroll
    for (int j = 7; j > 0; j--) {
        if (vs[j] > vs[j - 1]) {
            float tv = vs[j]; vs[j] = vs[j - 1]; vs[j - 1] = tv;
            int ti = is[j]; is[j] = is[j - 1]; is[j - 1] = ti;
        }
    }
}

__global__ __launch_bounds__(256) void topk_kernel(
    const float* __restrict__ coeffs, float* __restrict__ tkv,
    int* __restrict__ tki, float* __restrict__ spars_acc)
{
    __shared__ float sv[2624];
    __shared__ int   si[2624];
    int r = blockIdx.x, tid = threadIdx.x;
    const float* row = coeffs + (long long)r * MDICT;
    float vs[8]; int is[8];
#pragma unroll
    for (int j = 0; j < 8; j++) { vs[j] = -FLT_MAX; is[j] = -1; }
    for (int s = 0; s < MDICT / 256; s++) {
        int col = s * 256 + tid;
        ins8(row[col], col, vs, is);
    }
#pragma unroll
    for (int j = 0; j < 8; j++) { sv[tid * 8 + j] = vs[j]; si[tid * 8 + j] = is[j]; }
    __syncthreads();
    if (tid < 64) {
#pragma unroll
        for (int j = 0; j < 8; j++) { vs[j] = -FLT_MAX; is[j] = -1; }
        for (int e = tid * 32; e < tid * 32 + 32; e++) ins8(sv[e], si[e], vs, is);
#pragma unroll
        for (int j = 0; j < 8; j++) { sv[2048 + tid * 8 + j] = vs[j]; si[2048 + tid * 8 + j] = is[j]; }
    }
    __syncthreads();
    if (tid < 8) {
#pragma unroll
        for (int j = 0; j < 8; j++) { vs[j] = -FLT_MAX; is[j] = -1; }
        for (int e = 2048 + tid * 64; e < 2048 + tid * 64 + 64; e++) ins8(sv[e], si[e], vs, is);
#pragma unroll
        for (int j = 0; j < 8; j++) { sv[2560 + tid * 8 + j] = vs[j]; si[2560 + tid * 8 + j] = is[j]; }
    }
    __syncthreads();
    if (tid == 0) {
#pragma unroll
        for (int j = 0; j < 8; j++) { vs[j] = -FLT_MAX; is[j] = -1; }
        for (int e = 2560; e < 2624; e++) ins8(sv[e], si[e], vs, is);
        float s = 0.f;
#pragma unroll
        for (int j = 0; j < 8; j++) {
            tkv[r * 8 + j] = vs[j];
            tki[r * 8 + j] = is[j];
            s += fabsf(vs[j]);
        }
        atomicAdd(spars_acc, s);
    }
}

// -------- x_rec = basis + offset + bias ; norm1 -> normed (bf16) ---------
__global__ __launch_bounds__(256) void xrec_norm_kernel(
    const float* __restrict__ basis, const float* __restrict__ dictw,
    const float* __restrict__ bias, const float* __restrict__ nw,
    const float* __restrict__ tkv, const int* __restrict__ tki,
    unsigned short* __restrict__ normed_bf, float* __restrict__ e_acc)
{
    int r = blockIdx.x, tid = threadIdx.x;
    float vals[8]; int idxs[8];
#pragma unroll
    for (int j = 0; j < 8; j++) { vals[j] = tkv[r * 8 + j]; idxs[j] = tki[r * 8 + j]; }
    long long base = (long long)r * (D / 4) + tid;
    float4 acc = ((const float4*)basis)[base];
    float4 bv = ((const float4*)bias)[tid];
    acc.x += bv.x; acc.y += bv.y; acc.z += bv.z; acc.w += bv.w;
#pragma unroll
    for (int j = 0; j < 8; j++) {
        float4 dv = ((const float4*)dictw)[(long long)idxs[j] * (D / 4) + tid];
        float v = vals[j];
        acc.x += v * dv.x; acc.y += v * dv.y; acc.z += v * dv.z; acc.w += v * dv.w;
    }
    float ss = acc.x * acc.x + acc.y * acc.y + acc.z * acc.z + acc.w * acc.w;
    float tot = blk_sum(ss);
    float rms = sqrtf(tot / (float)D + 1e-6f);
    if (tid == 0) atomicAdd(e_acc, rms);
    float inv = 1.f / rms;
    float4 wv = ((const float4*)nw)[tid];
    uint2 o;
    o.x = (unsigned)f2bf(acc.x * wv.x * inv) | ((unsigned)f2bf(acc.y * wv.y * inv) << 16);
    o.y = (unsigned)f2bf(acc.z * wv.z * inv) | ((unsigned)f2bf(acc.w * wv.w * inv) << 16);
    ((uint2*)normed_bf)[base] = o;
}

// ---------------- rmsnorm2: fp32 in -> bf16 out ----------------
__global__ __launch_bounds__(256) void rmsnorm_kernel(
    const float* __restrict__ xin, const float* __restrict__ nw,
    unsigned short* __restrict__ xout_bf, float* __restrict__ e_acc)
{
    int r = blockIdx.x, tid = threadIdx.x;
    long long base = (long long)r * (D / 4) + tid;
    float4 v = ((const float4*)xin)[base];
    float ss = v.x * v.x + v.y * v.y + v.z * v.z + v.w * v.w;
    float tot = blk_sum(ss);
    float rms = sqrtf(tot / (float)D + 1e-6f);
    if (tid == 0) atomicAdd(e_acc, rms);
    float inv = 1.f / rms;
    float4 wv = ((const float4*)nw)[tid];
    uint2 o;
    o.x = (unsigned)f2bf(v.x * wv.x * inv) | ((unsigned)f2bf(v.y * wv.y * inv) << 16);
    o.y = (unsigned)f2bf(v.z * wv.z * inv) | ((unsigned)f2bf(v.w * wv.w * inv) << 16);
    ((uint2*)xout_bf)[base] = o;
}

// ------- k_mod[z,t,e] = sum_d k_bf[b,t,h*64+d] * rel[h,d,e]  (bf16 out) --
__global__ __launch_bounds__(256) void kmod_kernel(
    const unsigned short* __restrict__ kb, const float* __restrict__ rel,
    unsigned short* __restrict__ kmod_bf)
{
    __shared__ float Rs[64 * 64];
    int z = blockIdx.y;
    int b = z >> 4, h = z & 15;
    int tid = threadIdx.x;
    const float4* r4 = (const float4*)(rel + (long long)h * 4096);
    float4* Rs4 = (float4*)Rs;
#pragma unroll
    for (int i = 0; i < 4; i++) Rs4[tid + 256 * i] = r4[tid + 256 * i];
    __syncthreads();
    int e = tid & 63, tl = tid >> 6;
    int t = blockIdx.x * 4 + tl;
    const unsigned short* krow = kb + ((long long)(b * TT + t)) * D + h * DH;
    float acc = 0.f;
#pragma unroll
    for (int d4 = 0; d4 < 16; d4++) {
        uint2 p = *(const uint2*)&krow[d4 * 4];
        acc += bf2f(p.x & 0xFFFFu) * Rs[(d4 * 4 + 0) * 64 + e];
        acc += bf2f(p.x >> 16)     * Rs[(d4 * 4 + 1) * 64 + e];
        acc += bf2f(p.y & 0xFFFFu) * Rs[(d4 * 4 + 2) * 64 + e];
        acc += bf2f(p.y >> 16)     * Rs[(d4 * 4 + 3) * 64 + e];
    }
    kmod_bf[(long long)z * (TT * DH) + t * 64 + e] = f2bf(acc);
}

// ---- vT[z][d][t] = v_bf[b, t, h*64+d]  (64xTT per z, bf16) --------------
__global__ __launch_bounds__(256) void vtrans_kernel(
    const unsigned short* __restrict__ vb, unsigned short* __restrict__ vT)
{
    __shared__ unsigned short tile[64][68];
    int z = blockIdx.y, b = z >> 4, h = z & 15;
    int t0 = blockIdx.x * 64;
    int tid = threadIdx.x;
    int tr = tid >> 4;
    int dc = (tid & 15) * 4;
#pragma unroll
    for (int r = 0; r < 4; r++) {
        int t = tr + r * 16;
        uint2 p = *(const uint2*)&vb[((long long)(b * TT + t0 + t)) * D + h * DH + dc];
        tile[t][dc] = (unsigned short)(p.x & 0xFFFFu);
        tile[t][dc + 1] = (unsigned short)(p.x >> 16);
        tile[t][dc + 2] = (unsigned short)(p.y & 0xFFFFu);
        tile[t][dc + 3] = (unsigned short)(p.y >> 16);
    }
    __syncthreads();
#pragma unroll
    for (int r = 0; r < 4; r++) {
        int d = tr + r * 16;
        int t = (tid & 15) * 4;
        uint2 p;
        p.x = (unsigned)tile[t][d] | ((unsigned)tile[t + 1][d] << 16);
        p.y = (unsigned)tile[t + 2][d] | ((unsigned)tile[t + 3][d] << 16);
        *(uint2*)&vT[(long long)z * 64 * TT + (long long)d * TT + t0 + t] = p;
    }
}

// =======================================================================
// Fused flash-style attention: per block = (z, 128-row Q tile).
// Pass 1: S = Q @ Kmod^T (bf16 MFMA), thread-local online (m,l) over the
//         64 columns each thread owns; merge via lm-butterfly + LDS.
// Pass 2: recompute S, p = exp(s*0.125 - M)/L: write fp32 attn ONCE,
//         stash p as bf16 in LDS, accumulate ctx += p @ V via MFMA with
//         V^T fragments read directly from global (L2-resident).
// Replaces: scores GEMM (512MB write) + softmax (1GB R/W) + PV GEMM
// (512MB fp32 re-read + convert). Saves ~1.5GB HBM traffic.
// =======================================================================
__global__ __launch_bounds__(256, 2) void attn_fused_kernel(
    const unsigned short* __restrict__ qb,    // [4096][1024] bf16
    const unsigned short* __restrict__ kmod,  // [32][2048][64] bf16
    const unsigned short* __restrict__ vT,    // [32][64][2048] bf16
    float* __restrict__ attn,                 // [32][2048][2048] fp32 out
    unsigned short* __restrict__ ctx)         // [4096][1024] bf16 out
{
    constexpr int QS_LD = 72;    // pad 64->72 shorts: frag reads ~2-way banks
    constexpr int PS_LD = 136;   // pad 128->136 shorts
    __shared__ __align__(16) unsigned short Qs[128 * QS_LD];
    __shared__ __align__(16) unsigned short Ks[128 * QS_LD];
    __shared__ __align__(16) unsigned short Ps[128 * PS_LD];
    __shared__ float sm_h[2][128];
    __shared__ float sl_h[2][128];

    const int z = blockIdx.y;
    const int b = z >> 4, h = z & 15;
    const int q0 = blockIdx.x * 128;
    const int tid = threadIdx.x;
    const int lane = tid & 63;
    const int wave = tid >> 6;
    const int wr = wave >> 1, wc = wave & 1;
    const int lm = lane & 15, q4 = lane >> 4;
    const int kq = q4 * 8;

    // ---- load Q tile into padded LDS (reg-staged, 16B chunks) ----
    {
        const unsigned short* qbase = qb + ((long long)(b * TT + q0)) * D + h * DH;
#pragma unroll
        for (int rr = 0; rr < 4; rr++) {
            int q = rr * 256 + tid;          // 0..1023: 128 rows x 8 segs
            int row = q >> 3, seg = q & 7;
            short8 v = *(const short8*)(qbase + (long long)row * D + seg * 8);
            *(short8*)&Qs[row * QS_LD + seg * 8] = v;
        }
    }

    const unsigned short* kz = kmod + (long long)z * (TT * DH);

    float m_loc[4][4], l_loc[4][4];
#pragma unroll
    for (int i = 0; i < 4; i++)
#pragma unroll
        for (int r = 0; r < 4; r++) { m_loc[i][r] = -FLT_MAX; l_loc[i][r] = 0.f; }

    // ---------------- pass 1: exact row max + exp-sum (online) ----------
    for (int kt = 0; kt < 16; kt++) {
        __syncthreads();   // prev tile's fragment reads done
#pragma unroll
        for (int rr = 0; rr < 4; rr++) {
            int q = rr * 256 + tid;
            int row = q >> 3, seg = q & 7;
            short8 v = *(const short8*)(kz + (long long)(kt * 128 + row) * DH + seg * 8);
            *(short8*)&Ks[row * QS_LD + seg * 8] = v;
        }
        __syncthreads();
        f32x4 acc[4][4] = {};
#pragma unroll
        for (int ks = 0; ks < 2; ks++) {
            short8 af[4], bfk[4];
#pragma unroll
            for (int i = 0; i < 4; i++)
                af[i] = *(const short8*)&Qs[(wr * 64 + i * 16 + lm) * QS_LD + ks * 32 + kq];
#pragma unroll
            for (int j = 0; j < 4; j++)
                bfk[j] = *(const short8*)&Ks[(wc * 64 + j * 16 + lm) * QS_LD + ks * 32 + kq];
#pragma unroll
            for (int i = 0; i < 4; i++)
#pragma unroll
                for (int j = 0; j < 4; j++)
                    acc[i][j] = __builtin_amdgcn_mfma_f32_16x16x32_bf16(af[i], bfk[j], acc[i][j], 0, 0, 0);
        }
#pragma unroll
        for (int i = 0; i < 4; i++)
#pragma unroll
            for (int r = 0; r < 4; r++) {
                float v0 = acc[i][0][r] * 0.125f;
                float v1 = acc[i][1][r] * 0.125f;
                float v2 = acc[i][2][r] * 0.125f;
                float v3 = acc[i][3][r] * 0.125f;
                float tmax = fmaxf(fmaxf(v0, v1), fmaxf(v2, v3));
                float mo = m_loc[i][r];
                float mn = fmaxf(mo, tmax);
                l_loc[i][r] = l_loc[i][r] * __expf(mo - mn)
                            + __expf(v0 - mn) + __expf(v1 - mn)
                            + __expf(v2 - mn) + __expf(v3 - mn);
                m_loc[i][r] = mn;
            }
    }

    // merge across the 16 lm lanes (each thread's stats cover its 4 j-cols
    // x 16 tiles; butterfly over lm covers the wave's 64-col half)
#pragma unroll
    for (int off = 1; off <= 8; off <<= 1) {
#pragma unroll
        for (int i = 0; i < 4; i++)
#pragma unroll
            for (int r = 0; r < 4; r++) {
                float mo = __shfl_xor(m_loc[i][r], off);
                float lo = __shfl_xor(l_loc[i][r], off);
                float mn = fmaxf(m_loc[i][r], mo);
                l_loc[i][r] = l_loc[i][r] * __expf(m_loc[i][r] - mn) + lo * __expf(mo - mn);
                m_loc[i][r] = mn;
            }
    }
    // merge across the two wc half-columns via LDS
    if (lm == 0) {
#pragma unroll
        for (int i = 0; i < 4; i++)
#pragma unroll
            for (int r = 0; r < 4; r++) {
                int row = wr * 64 + i * 16 + q4 * 4 + r;
                sm_h[wc][row] = m_loc[i][r];
                sl_h[wc][row] = l_loc[i][r];
            }
    }
    __syncthreads();
    float Mf[4][4], Linv[4][4];
#pragma unroll
    for (int i = 0; i < 4; i++)
#pragma unroll
        for (int r = 0; r < 4; r++) {
            int row = wr * 64 + i * 16 + q4 * 4 + r;
            float m0 = sm_h[0][row], m1 = sm_h[1][row];
            float l0 = sl_h[0][row], l1 = sl_h[1][row];
            float mn = fmaxf(m0, m1);
            float L = l0 * __expf(m0 - mn) + l1 * __expf(m1 - mn);
            Mf[i][r] = mn;
            Linv[i][r] = 1.f / L;
        }

    // ---------------- pass 2: p -> attn (fp32, once) + PV ---------------
    const unsigned short* vz = vT + (long long)z * (64 * TT);
    float* az = attn + (long long)z * ((long long)TT * TT);
    f32x4 acc_o[4][2] = {};

    for (int kt = 0; kt < 16; kt++) {
        __syncthreads();   // prev PV reads of Ps/Ks done
#pragma unroll
        for (int rr = 0; rr < 4; rr++) {
            int q = rr * 256 + tid;
            int row = q >> 3, seg = q & 7;
            short8 v = *(const short8*)(kz + (long long)(kt * 128 + row) * DH + seg * 8);
            *(short8*)&Ks[row * QS_LD + seg * 8] = v;
        }
        // preload V^T fragments for this tile (L2-resident)
        short8 bv[2][4];
#pragma unroll
        for (int j = 0; j < 2; j++)
#pragma unroll
            for (int ks = 0; ks < 4; ks++)
                bv[j][ks] = *(const short8*)(vz + (long long)(wc * 32 + j * 16 + lm) * TT
                                             + kt * 128 + ks * 32 + kq);
        __syncthreads();
        f32x4 acc[4][4] = {};
#pragma unroll
        for (int ks = 0; ks < 2; ks++) {
            short8 af[4], bfk[4];
#pragma unroll
            for (int i = 0; i < 4; i++)
                af[i] = *(const short8*)&Qs[(wr * 64 + i * 16 + lm) * QS_LD + ks * 32 + kq];
#pragma unroll
            for (int j = 0; j < 4; j++)
                bfk[j] = *(const short8*)&Ks[(wc * 64 + j * 16 + lm) * QS_LD + ks * 32 + kq];
#pragma unroll
            for (int i = 0; i < 4; i++)
#pragma unroll
                for (int j = 0; j < 4; j++)
                    acc[i][j] = __builtin_amdgcn_mfma_f32_16x16x32_bf16(af[i], bfk[j], acc[i][j], 0, 0, 0);
        }
        // p: normalize, write attn (only write of this buffer), stash bf16
#pragma unroll
        for (int i = 0; i < 4; i++)
#pragma unroll
            for (int r = 0; r < 4; r++) {
                int row = wr * 64 + i * 16 + q4 * 4 + r;
                float* arow = az + (long long)(q0 + row) * TT + kt * 128 + wc * 64 + lm;
#pragma unroll
                for (int j = 0; j < 4; j++) {
                    float p = __expf(acc[i][j][r] * 0.125f - Mf[i][r]) * Linv[i][r];
                    arow[j * 16] = p;
                    Ps[row * PS_LD + wc * 64 + j * 16 + lm] = f2bf(p);
                }
            }
        __syncthreads();   // Ps visible to all waves
        // PV: ctx[q][dh] += sum_t P[q][t] * V^T[dh][t]
#pragma unroll
        for (int ks = 0; ks < 4; ks++) {
            short8 paf[4];
#pragma unroll
            for (int i = 0; i < 4; i++)
                paf[i] = *(const short8*)&Ps[(wr * 64 + i * 16 + lm) * PS_LD + ks * 32 + kq];
#pragma unroll
            for (int i = 0; i < 4; i++)
#pragma unroll
                for (int j = 0; j < 2; j++)
                    acc_o[i][j] = __builtin_amdgcn_mfma_f32_16x16x32_bf16(paf[i], bv[j][ks], acc_o[i][j], 0, 0, 0);
        }
    }

    // ---- ctx epilogue (bf16) ----
#pragma unroll
    for (int i = 0; i < 4; i++)
#pragma unroll
        for (int r = 0; r < 4; r++) {
            int row = wr * 64 + i * 16 + q4 * 4 + r;
            long long crow = ((long long)(b * TT + q0 + row)) * D + h * DH;
#pragma unroll
            for (int j = 0; j < 2; j++)
                ctx[crow + wc * 32 + j * 16 + lm] = f2bf(acc_o[i][j][r]);
        }
}

// ------- h = sigmoid(g) * silu(u), bf16 in, bf16 out in place into g -----
__global__ __launch_bounds__(256) void gateup_kernel(
    unsigned short* __restrict__ g, const unsigned short* __restrict__ u, long long n4)
{
    long long i = (long long)blockIdx.x * 256 + threadIdx.x;
    long long stride = (long long)gridDim.x * 256;
    for (; i < n4; i += stride) {
        uint2 gp = ((uint2*)g)[i];
        uint2 up = ((const uint2*)u)[i];
        float gv[4] = { bf2f(gp.x & 0xFFFFu), bf2f(gp.x >> 16), bf2f(gp.y & 0xFFFFu), bf2f(gp.y >> 16) };
        float uv[4] = { bf2f(up.x & 0xFFFFu), bf2f(up.x >> 16), bf2f(up.y & 0xFFFFu), bf2f(up.y >> 16) };
        unsigned short hh[4];
#pragma unroll
        for (int j = 0; j < 4; j++) {
            float r = (1.f / (1.f + __expf(-gv[j]))) * uv[j] * (1.f / (1.f + __expf(-uv[j])));
            hh[j] = f2bf(r);
        }
        uint2 o;
        o.x = (unsigned)hh[0] | ((unsigned)hh[1] << 16);
        o.y = (unsigned)hh[2] | ((unsigned)hh[3] << 16);
        ((uint2*)g)[i] = o;
    }
}

// ---------------- finalize scalars ----------------
__global__ void finalize_kernel(const float* __restrict__ scal, float* __restrict__ out)
{
    out[OUT_SPARS] = scal[0] / (float)((double)ROWS * (double)MDICT);
    out[OUT_E1] = scal[1] / (float)ROWS;
    out[OUT_E2] = scal[2] / (float)ROWS;
}

extern "C" void kernel_launch(void* const* d_in, const int* in_sizes, int n_in,
                              void* d_out, int out_size, void* d_ws, size_t ws_size,
                              hipStream_t stream) {
    const float* x     = (const float*)d_in[0];
    const float* proto = (const float*)d_in[2];
    const float* fgw   = (const float*)d_in[3];
    const float* dictw = (const float*)d_in[4];
    const float* encw  = (const float*)d_in[5];
    const float* wq    = (const float*)d_in[6];
    const float* wk    = (const float*)d_in[7];
    const float* wv    = (const float*)d_in[8];
    const float* wo    = (const float*)d_in[9];
    const float* rel   = (const float*)d_in[10];
    const float* gatew = (const float*)d_in[11];
    const float* upw   = (const float*)d_in[12];
    const float* downw = (const float*)d_in[13];
    const float* n1w   = (const float*)d_in[14];
    const float* n2w   = (const float*)d_in[15];
    const float* bias  = (const float*)d_in[16];
    float* out = (float*)d_out;
    float* ws  = (float*)d_ws;

    // ---- ws arena (float offsets; bf16 buffers sized n/2 floats) ----
    float*          basisf  = ws + 0;                 // 4.2M fl (also xmid)
    unsigned short* kb_bf   = (unsigned short*)(ws + 4194304);   // 4096x1024
    unsigned short* resid_bf= (unsigned short*)(ws + 6291456);   // also ctx_bf
    unsigned short* norm_bf = (unsigned short*)(ws + 8388608);   // normed / normed2
    unsigned short* qb_bf   = (unsigned short*)(ws + 10485760);
    unsigned short* vb_bf   = (unsigned short*)(ws + 12582912);
    unsigned short* kmod_bf = (unsigned short*)(ws + 14680064);
    unsigned short* vT_bf   = (unsigned short*)(ws + 16777216);
    unsigned short* encw_bf = (unsigned short*)(ws + 18874368);  // also gate_bf (h)
    unsigned short* up_bf   = (unsigned short*)(ws + 27262976);
    unsigned short* wq_bf   = (unsigned short*)(ws + 35651584);
    unsigned short* wk_bf   = (unsigned short*)(ws + 36175872);
    unsigned short* wv_bf   = (unsigned short*)(ws + 36700160);
    unsigned short* wo_bf   = (unsigned short*)(ws + 37224448);
    unsigned short* gatew_bf= (unsigned short*)(ws + 37748736);
    unsigned short* upw_bf  = (unsigned short*)(ws + 39845888);
    unsigned short* downw_bf= (unsigned short*)(ws + 41943040);
    float*          tkv     = ws + 44040192;
    int*            tki     = (int*)(ws + 44072960);
    float*          scal    = ws + 44105728;
    unsigned short* ctx_bf  = resid_bf;
    unsigned short* gate_bf = encw_bf;
    float*          xmid    = basisf;

    float* fs   = out + OUT_FS;
    float* attn = out + OUT_ATTN;
    float* coeffs = attn;            // scratch until attn scores written

    hipMemsetAsync(scal, 0, 3 * sizeof(float), stream);

    // weight conversions (fp32 -> bf16)
    cvt_bf16_kernel<<<2048, 256, 0, stream>>>(encw, encw_bf, (long long)MDICT * D / 4);
    cvt_bf16_kernel<<<256, 256, 0, stream>>>(wq, wq_bf, (long long)D * D / 4);
    cvt_bf16_kernel<<<256, 256, 0, stream>>>(wk, wk_bf, (long long)D * D / 4);
    cvt_bf16_kernel<<<256, 256, 0, stream>>>(wv, wv_bf, (long long)D * D / 4);
    cvt_bf16_kernel<<<256, 256, 0, stream>>>(wo, wo_bf, (long long)D * D / 4);
    cvt_bf16_kernel<<<1024, 256, 0, stream>>>(gatew, gatew_bf, (long long)DFF * D / 4);
    cvt_bf16_kernel<<<1024, 256, 0, stream>>>(upw, upw_bf, (long long)DFF * D / 4);
    cvt_bf16_kernel<<<1024, 256, 0, stream>>>(downw, downw_bf, (long long)D * DFF / 4);

    family_kernel<<<ROWS, 64, 0, stream>>>(x, fgw, fs);
    basis_kernel<<<ROWS, 256, 0, stream>>>(x, fs, proto, basisf, resid_bf);
    // coeffs[4096,16384] = resid @ enc_w^T
    gemm_mfma<128, 128, false, false><<<dim3(128, 32, 1), 256, 0, stream>>>(
        resid_bf, encw_bf, coeffs, nullptr, D, D, D, MDICT, 1.f, 1, 0, 0, 0, 0, 0, 0);
    topk_kernel<<<ROWS, 256, 0, stream>>>(coeffs, tkv, tki, scal + 0);
    xrec_norm_kernel<<<ROWS, 256, 0, stream>>>(basisf, dictw, bias, n1w, tkv, tki, norm_bf, scal + 1);
    // q,k,v [4096,1024] bf16
    gemm_mfma<128, 128, true, false><<<dim3(8, 32, 1), 256, 0, stream>>>(
        norm_bf, wq_bf, qb_bf, nullptr, D, D, D, D, 1.f, 1, 0, 0, 0, 0, 0, 0);
    gemm_mfma<128, 128, true, false><<<dim3(8, 32, 1), 256, 0, stream>>>(
        norm_bf, wk_bf, kb_bf, nullptr, D, D, D, D, 1.f, 1, 0, 0, 0, 0, 0, 0);
    gemm_mfma<128, 128, true, false><<<dim3(8, 32, 1), 256, 0, stream>>>(
        norm_bf, wv_bf, vb_bf, nullptr, D, D, D, D, 1.f, 1, 0, 0, 0, 0, 0, 0);
    kmod_kernel<<<dim3(TT / 4, 32), 256, 0, stream>>>(kb_bf, rel, kmod_bf);
    vtrans_kernel<<<dim3(TT / 64, 32), 256, 0, stream>>>(vb_bf, vT_bf);
    // fused attention: scores + softmax + PV in one kernel.
    // attn written exactly once (fp32), ctx_bf produced for wo GEMM.
    attn_fused_kernel<<<dim3(TT / 128, 32), 256, 0, stream>>>(
        qb_bf, kmod_bf, vT_bf, attn, ctx_bf);
    // xmid = ctx @ wo^T + x  (fp32)
    gemm_mfma<128, 128, false, false><<<dim3(8, 32, 1), 256, 0, stream>>>(
        ctx_bf, wo_bf, xmid, x, D, D, D, D, 1.f, 1, 0, 0, 0, 0, 0, 0);
    rmsnorm_kernel<<<ROWS, 256, 0, stream>>>(xmid, n2w, norm_bf, scal + 2);
    // gate/up [4096,4096] bf16
    gemm_mfma<128, 128, true, false><<<dim3(32, 32, 1), 256, 0, stream>>>(
        norm_bf, gatew_bf, gate_bf, nullptr, D, D, D, DFF, 1.f, 1, 0, 0, 0, 0, 0, 0);
    gemm_mfma<128, 128, true, false><<<dim3(32, 32, 1), 256, 0, stream>>>(
        norm_bf, upw_bf, up_bf, nullptr, D, D, D, DFF, 1.f, 1, 0, 0, 0, 0, 0, 0);
    gateup_kernel<<<4096, 256, 0, stream>>>(gate_bf, up_bf, (long long)ROWS * DFF / 4);
    // out_x = h @ down^T + xmid (fp32)
    gemm_mfma<128, 128, false, false><<<dim3(8, 32, 1), 256, 0, stream>>>(
        gate_bf, downw_bf, out + OUT_X, xmid, DFF, DFF, DFF, D, 1.f, 1, 0, 0, 0, 0, 0, 0);
    finalize_kernel<<<1, 1, 0, stream>>>(scal, out);
}

// Round 2
// 1943.742 us; speedup vs baseline: 1.1768x; 1.0423x over previous
//
#include <hip/hip_runtime.h>
#include <float.h>
#include <math.h>

#define D 1024
#define NF 64
#define MDICT 16384
#define NH 16
#define DH 64
#define TT 2048
#define ROWS 4096   // B*T
#define DFF 4096
#define QKV_LD 3072 // merged q|k|v row stride (shorts)

// d_out layout (floats)
#define OUT_X     0LL
#define OUT_ATTN  4194304LL
#define OUT_FS    138412032LL
#define OUT_SPARS 138674176LL
#define OUT_E1    138674177LL
#define OUT_E2    138674178LL

typedef __attribute__((ext_vector_type(8))) short short8;
typedef __attribute__((ext_vector_type(4))) float f32x4;

__device__ inline unsigned short f2bf(float f) {
    unsigned int u = __float_as_uint(f);
    u = u + 0x7FFFu + ((u >> 16) & 1u);   // round-to-nearest-even (finite vals)
    return (unsigned short)(u >> 16);
}
__device__ inline float bf2f(unsigned int s) {
    return __uint_as_float(s << 16);
}

// bijective XCD swizzle (m204 form): contiguous chunk of the grid per XCD
__device__ inline int xcd_swz(int wg, int nwg) {
    int q = nwg >> 3, r = nwg & 7;
    int xcd = wg & 7, loc = wg >> 3;
    return (xcd < r ? xcd * (q + 1) : r * (q + 1) + (xcd - r) * q) + loc;
}

// ---------------- block reduce helpers (blockDim == 256) ----------------
__device__ inline float blk_sum(float v) {
    __shared__ float sb[4];
    int lane = threadIdx.x & 63, w = threadIdx.x >> 6;
#pragma unroll
    for (int o = 32; o; o >>= 1) v += __shfl_down(v, o);
    if (lane == 0) sb[w] = v;
    __syncthreads();
    float s = sb[0] + sb[1] + sb[2] + sb[3];
    __syncthreads();
    return s;
}

// =======================================================================
// bf16 MFMA GEMM: C = alpha * A @ B^T (+ addC).  A:[M,K] B:[N,K] row-major.
// BK=32, 256 threads = 4 waves in 2x2; wave tile (BM/2)x(BN/2) of 16x16x32
// MFMAs. A/B staged via global_load_lds (16B). XCD-swizzled block mapping.
// =======================================================================
template<int BM, int BN, bool OBF>
__global__ __launch_bounds__(256) void gemm_mfma(
    const unsigned short* __restrict__ Ab, const unsigned short* __restrict__ Bb,
    void* __restrict__ Cbv, const float* __restrict__ addCb,
    int K, int lda, int ldb, int ldc, float alpha)
{
    int nwg = gridDim.x * gridDim.y;
    int wg = blockIdx.y * gridDim.x + blockIdx.x;
    int swz = xcd_swz(wg, nwg);
    int bx = swz % (int)gridDim.x, by = swz / (int)gridDim.x;

    const unsigned short* B = Bb;
    const float* addC = addCb;

    __shared__ __align__(16) unsigned short As[BM * 32];
    __shared__ __align__(16) unsigned short Bs[BN * 32];

    int tid = threadIdx.x;
    int lane = tid & 63, wave = tid >> 6;
    int wr = wave >> 1, wc = wave & 1;
    long long r0 = (long long)by * BM;
    long long c0 = (long long)bx * BN;

    constexpr int TI = BM / 32;
    constexpr int TJ = BN / 32;
    constexpr int RA = BM * 4 / 256;
    constexpr int RB = BN * 4 / 256;

    f32x4 acc[TI][TJ] = {};
    int lm = lane & 15;
    int kq = (lane >> 4) * 8;

    for (int k0 = 0; k0 < K; k0 += 32) {
        __syncthreads();
#pragma unroll
        for (int r = 0; r < RB; r++) {
            int q = r * 256 + tid;
            const unsigned short* gp = B + (c0 + (q >> 2)) * (long long)ldb + k0 + (q & 3) * 8;
            unsigned short* lp = Bs + (r * 256 + (tid & 192)) * 8;
            __builtin_amdgcn_global_load_lds(
                (const __attribute__((address_space(1))) void*)gp,
                (__attribute__((address_space(3))) void*)lp, 16, 0, 0);
        }
#pragma unroll
        for (int r = 0; r < RA; r++) {
            int q = r * 256 + tid;
            const unsigned short* gp = Ab + (r0 + (q >> 2)) * (long long)lda + k0 + (q & 3) * 8;
            unsigned short* lp = As + (r * 256 + (tid & 192)) * 8;
            __builtin_amdgcn_global_load_lds(
                (const __attribute__((address_space(1))) void*)gp,
                (__attribute__((address_space(3))) void*)lp, 16, 0, 0);
        }
        __syncthreads();
        short8 af[TI], bfr[TJ];
#pragma unroll
        for (int i = 0; i < TI; i++)
            af[i] = *(const short8*)&As[(wr * (BM / 2) + i * 16 + lm) * 32 + kq];
#pragma unroll
        for (int j = 0; j < TJ; j++)
            bfr[j] = *(const short8*)&Bs[(wc * (BN / 2) + j * 16 + lm) * 32 + kq];
#pragma unroll
        for (int i = 0; i < TI; i++)
#pragma unroll
            for (int j = 0; j < TJ; j++)
                acc[i][j] = __builtin_amdgcn_mfma_f32_16x16x32_bf16(af[i], bfr[j], acc[i][j], 0, 0, 0);
    }

#pragma unroll
    for (int i = 0; i < TI; i++) {
#pragma unroll
        for (int r = 0; r < 4; r++) {
            long long row = r0 + wr * (BM / 2) + i * 16 + (lane >> 4) * 4 + r;
#pragma unroll
            for (int j = 0; j < TJ; j++) {
                long long col = c0 + wc * (BN / 2) + j * 16 + lm;
                long long idx = row * (long long)ldc + col;
                float v = alpha * acc[i][j][r];
                if (addC) v += addC[idx];
                if (OBF) ((unsigned short*)Cbv)[idx] = f2bf(v);
                else     ((float*)Cbv)[idx] = v;
            }
        }
    }
}

// ---------------- top-8 insert helper ----------------
__device__ inline void ins8(float v, int idx, float* vs, int* is) {
    if (v <= vs[7]) return;
    vs[7] = v; is[7] = idx;
#pragma unroll
    for (int j = 7; j > 0; j--) {
        if (vs[j] > vs[j - 1]) {
            float tv = vs[j]; vs[j] = vs[j - 1]; vs[j - 1] = tv;
            int ti = is[j]; is[j] = is[j - 1]; is[j - 1] = ti;
        }
    }
}

// =======================================================================
// Encoder GEMM + fused per-tile top-8: S = resid @ enc^T (128x128 tile),
// never written to global. Per-block, per-row top-8 candidates written to
// cand (exact: row top-8 is contained in union of tile top-8s).
// =======================================================================
__global__ __launch_bounds__(256) void gemm_topk(
    const unsigned short* __restrict__ Ab, const unsigned short* __restrict__ Bb,
    float* __restrict__ cand_v, int* __restrict__ cand_i)
{
    constexpr int BM = 128, BN = 128;
    constexpr int NBX = MDICT / BN;   // 128 column tiles
    int nwg = gridDim.x * gridDim.y;
    int wg = blockIdx.y * gridDim.x + blockIdx.x;
    int swz = xcd_swz(wg, nwg);
    int bx = swz % (int)gridDim.x, by = swz / (int)gridDim.x;

    __shared__ __align__(16) unsigned short As[BM * 32];
    __shared__ __align__(16) unsigned short Bs[BN * 32];
    __shared__ float Sv[64 * 133];    // half-tile scores, pad 133 (~4-way)

    int tid = threadIdx.x;
    int lane = tid & 63, wave = tid >> 6;
    int wr = wave >> 1, wc = wave & 1;
    long long r0 = (long long)by * BM;
    long long c0 = (long long)bx * BN;

    f32x4 acc[4][4] = {};
    int lm = lane & 15;
    int q4 = lane >> 4;
    int kq = q4 * 8;

    for (int k0 = 0; k0 < D; k0 += 32) {
        __syncthreads();
#pragma unroll
        for (int r = 0; r < 2; r++) {
            int q = r * 256 + tid;
            const unsigned short* gp = Bb + (c0 + (q >> 2)) * (long long)D + k0 + (q & 3) * 8;
            unsigned short* lp = Bs + (r * 256 + (tid & 192)) * 8;
            __builtin_amdgcn_global_load_lds(
                (const __attribute__((address_space(1))) void*)gp,
                (__attribute__((address_space(3))) void*)lp, 16, 0, 0);
        }
#pragma unroll
        for (int r = 0; r < 2; r++) {
            int q = r * 256 + tid;
            const unsigned short* gp = Ab + (r0 + (q >> 2)) * (long long)D + k0 + (q & 3) * 8;
            unsigned short* lp = As + (r * 256 + (tid & 192)) * 8;
            __builtin_amdgcn_global_load_lds(
                (const __attribute__((address_space(1))) void*)gp,
                (__attribute__((address_space(3))) void*)lp, 16, 0, 0);
        }
        __syncthreads();
        short8 af[4], bfr[4];
#pragma unroll
        for (int i = 0; i < 4; i++)
            af[i] = *(const short8*)&As[(wr * 64 + i * 16 + lm) * 32 + kq];
#pragma unroll
        for (int j = 0; j < 4; j++)
            bfr[j] = *(const short8*)&Bs[(wc * 64 + j * 16 + lm) * 32 + kq];
#pragma unroll
        for (int i = 0; i < 4; i++)
#pragma unroll
            for (int j = 0; j < 4; j++)
                acc[i][j] = __builtin_amdgcn_mfma_f32_16x16x32_bf16(af[i], bfr[j], acc[i][j], 0, 0, 0);
    }

    // ---- fused top-8 epilogue: two 64-row phases through Sv ----
#pragma unroll
    for (int h = 0; h < 2; h++) {
        __syncthreads();                     // Sv free (or prev phase done)
        if (wr == h) {
#pragma unroll
            for (int i = 0; i < 4; i++)
#pragma unroll
                for (int r = 0; r < 4; r++)
#pragma unroll
                    for (int j = 0; j < 4; j++)
                        Sv[(i * 16 + q4 * 4 + r) * 133 + wc * 64 + j * 16 + lm] = acc[i][j][r];
        }
        __syncthreads();
        int row_loc = tid >> 2, sub = tid & 3;   // 4 threads per row, 32 cols each
        float vs[8]; int is[8];
#pragma unroll
        for (int k = 0; k < 8; k++) { vs[k] = -FLT_MAX; is[k] = -1; }
        const float* Srow = &Sv[row_loc * 133 + sub * 32];
        int cbase = (int)c0 + sub * 32;
        for (int c = 0; c < 32; c++) ins8(Srow[c], cbase + c, vs, is);
        // merge 4 sub-lists via shfl (tid, tid^1, tid^2 same wave)
#pragma unroll
        for (int step = 1; step <= 2; step <<= 1) {
            float ov[8]; int oi[8];
#pragma unroll
            for (int k = 0; k < 8; k++) { ov[k] = __shfl_xor(vs[k], step); oi[k] = __shfl_xor(is[k], step); }
#pragma unroll
            for (int k = 0; k < 8; k++) ins8(ov[k], oi[k], vs, is);
        }
        if (sub == 0) {
            long long grow = r0 + h * 64 + row_loc;
#pragma unroll
            for (int k = 0; k < 8; k++) {
                cand_v[grow * (NBX * 8) + bx * 8 + k] = vs[k];
                cand_i[grow * (NBX * 8) + bx * 8 + k] = is[k];
            }
        }
    }
}

// ------- final exact top-8 over 1024 candidates per row ------------------
__global__ __launch_bounds__(256) void topk_reduce_kernel(
    const float* __restrict__ cand_v, const int* __restrict__ cand_i,
    float* __restrict__ tkv, int* __restrict__ tki, float* __restrict__ spars_acc)
{
    __shared__ float sv[2624];
    __shared__ int   si[2624];
    int r = blockIdx.x, tid = threadIdx.x;
    float4 cv = ((const float4*)(cand_v + (long long)r * 1024))[tid];
    int4   ci = ((const int4*)(cand_i + (long long)r * 1024))[tid];
    float vs[8]; int is[8];
#pragma unroll
    for (int j = 0; j < 8; j++) { vs[j] = -FLT_MAX; is[j] = -1; }
    ins8(cv.x, ci.x, vs, is); ins8(cv.y, ci.y, vs, is);
    ins8(cv.z, ci.z, vs, is); ins8(cv.w, ci.w, vs, is);
#pragma unroll
    for (int j = 0; j < 8; j++) { sv[tid * 8 + j] = vs[j]; si[tid * 8 + j] = is[j]; }
    __syncthreads();
    if (tid < 64) {
#pragma unroll
        for (int j = 0; j < 8; j++) { vs[j] = -FLT_MAX; is[j] = -1; }
        for (int e = tid * 32; e < tid * 32 + 32; e++) ins8(sv[e], si[e], vs, is);
#pragma unroll
        for (int j = 0; j < 8; j++) { sv[2048 + tid * 8 + j] = vs[j]; si[2048 + tid * 8 + j] = is[j]; }
    }
    __syncthreads();
    if (tid < 8) {
#pragma unroll
        for (int j = 0; j < 8; j++) { vs[j] = -FLT_MAX; is[j] = -1; }
        for (int e = 2048 + tid * 64; e < 2048 + tid * 64 + 64; e++) ins8(sv[e], si[e], vs, is);
#pragma unroll
        for (int j = 0; j < 8; j++) { sv[2560 + tid * 8 + j] = vs[j]; si[2560 + tid * 8 + j] = is[j]; }
    }
    __syncthreads();
    if (tid == 0) {
#pragma unroll
        for (int j = 0; j < 8; j++) { vs[j] = -FLT_MAX; is[j] = -1; }
        for (int e = 2560; e < 2624; e++) ins8(sv[e], si[e], vs, is);
        float s = 0.f;
#pragma unroll
        for (int j = 0; j < 8; j++) {
            tkv[r * 8 + j] = vs[j];
            tki[r * 8 + j] = is[j];
            s += fabsf(vs[j]);
        }
        atomicAdd(spars_acc, s);
    }
}

// ---------------- fp32 -> bf16 convert (grid-stride, 4/thread) -----------
__global__ __launch_bounds__(256) void cvt_bf16_kernel(
    const float* __restrict__ in, unsigned short* __restrict__ out, long long n4)
{
    long long i = (long long)blockIdx.x * 256 + threadIdx.x;
    long long stride = (long long)gridDim.x * 256;
    for (; i < n4; i += stride) {
        float4 v = ((const float4*)in)[i];
        uint2 p;
        p.x = (unsigned)f2bf(v.x) | ((unsigned)f2bf(v.y) << 16);
        p.y = (unsigned)f2bf(v.z) | ((unsigned)f2bf(v.w) << 16);
        ((uint2*)out)[i] = p;
    }
}

// ---------------- family gate: logits + softmax ----------------
__global__ __launch_bounds__(64) void family_kernel(
    const float* __restrict__ x, const float* __restrict__ fgw,
    float* __restrict__ fs_out)
{
    __shared__ float xs[D];
    int r = blockIdx.x, f = threadIdx.x;
    const float4* x4 = (const float4*)(x + (long long)r * D);
    float4* xs4 = (float4*)xs;
#pragma unroll
    for (int i = 0; i < 4; i++) xs4[f + 64 * i] = x4[f + 64 * i];
    __syncthreads();
    const float4* w4 = (const float4*)(fgw + (long long)f * D);
    float acc = 0.f;
#pragma unroll 8
    for (int d = 0; d < D / 4; d++) {
        float4 w = w4[d];
        float4 xv = xs4[d];
        acc += w.x * xv.x + w.y * xv.y + w.z * xv.z + w.w * xv.w;
    }
    float mx = acc;
#pragma unroll
    for (int o = 32; o; o >>= 1) mx = fmaxf(mx, __shfl_xor(mx, o));
    float e = __expf(acc - mx);
    float s = e;
#pragma unroll
    for (int o = 32; o; o >>= 1) s += __shfl_xor(s, o);
    fs_out[(long long)r * NF + f] = e / s;
}

// ------- basis = fs @ proto (fp32 out) ; resid = x - basis (bf16 out) ----
__global__ __launch_bounds__(256) void basis_kernel(
    const float* __restrict__ x, const float* __restrict__ fs,
    const float* __restrict__ proto, float* __restrict__ basis,
    unsigned short* __restrict__ resid_bf)
{
    __shared__ float Ss[NF];
    int r = blockIdx.x, tid = threadIdx.x;
    if (tid < NF) Ss[tid] = fs[(long long)r * NF + tid];
    __syncthreads();
    float4 acc = {0.f, 0.f, 0.f, 0.f};
    const float4* p4 = (const float4*)proto;
#pragma unroll 8
    for (int k = 0; k < NF; k++) {
        float s = Ss[k];
        float4 p = p4[k * (D / 4) + tid];
        acc.x += s * p.x; acc.y += s * p.y; acc.z += s * p.z; acc.w += s * p.w;
    }
    long long base = (long long)r * (D / 4) + tid;
    float4 xv = ((const float4*)x)[base];
    ((float4*)basis)[base] = acc;
    uint2 rp;
    rp.x = (unsigned)f2bf(xv.x - acc.x) | ((unsigned)f2bf(xv.y - acc.y) << 16);
    rp.y = (unsigned)f2bf(xv.z - acc.z) | ((unsigned)f2bf(xv.w - acc.w) << 16);
    ((uint2*)resid_bf)[base] = rp;
}

// -------- x_rec = basis + offset + bias ; norm1 -> normed (bf16) ---------
__global__ __launch_bounds__(256) void xrec_norm_kernel(
    const float* __restrict__ basis, const float* __restrict__ dictw,
    const float* __restrict__ bias, const float* __restrict__ nw,
    const float* __restrict__ tkv, const int* __restrict__ tki,
    unsigned short* __restrict__ normed_bf, float* __restrict__ e_acc)
{
    int r = blockIdx.x, tid = threadIdx.x;
    float vals[8]; int idxs[8];
#pragma unroll
    for (int j = 0; j < 8; j++) { vals[j] = tkv[r * 8 + j]; idxs[j] = tki[r * 8 + j]; }
    long long base = (long long)r * (D / 4) + tid;
    float4 acc = ((const float4*)basis)[base];
    float4 bv = ((const float4*)bias)[tid];
    acc.x += bv.x; acc.y += bv.y; acc.z += bv.z; acc.w += bv.w;
#pragma unroll
    for (int j = 0; j < 8; j++) {
        float4 dv = ((const float4*)dictw)[(long long)idxs[j] * (D / 4) + tid];
        float v = vals[j];
        acc.x += v * dv.x; acc.y += v * dv.y; acc.z += v * dv.z; acc.w += v * dv.w;
    }
    float ss = acc.x * acc.x + acc.y * acc.y + acc.z * acc.z + acc.w * acc.w;
    float tot = blk_sum(ss);
    float rms = sqrtf(tot / (float)D + 1e-6f);
    if (tid == 0) atomicAdd(e_acc, rms);
    float inv = 1.f / rms;
    float4 wv = ((const float4*)nw)[tid];
    uint2 o;
    o.x = (unsigned)f2bf(acc.x * wv.x * inv) | ((unsigned)f2bf(acc.y * wv.y * inv) << 16);
    o.y = (unsigned)f2bf(acc.z * wv.z * inv) | ((unsigned)f2bf(acc.w * wv.w * inv) << 16);
    ((uint2*)normed_bf)[base] = o;
}

// ---------------- rmsnorm2: fp32 in -> bf16 out ----------------
__global__ __launch_bounds__(256) void rmsnorm_kernel(
    const float* __restrict__ xin, const float* __restrict__ nw,
    unsigned short* __restrict__ xout_bf, float* __restrict__ e_acc)
{
    int r = blockIdx.x, tid = threadIdx.x;
    long long base = (long long)r * (D / 4) + tid;
    float4 v = ((const float4*)xin)[base];
    float ss = v.x * v.x + v.y * v.y + v.z * v.z + v.w * v.w;
    float tot = blk_sum(ss);
    float rms = sqrtf(tot / (float)D + 1e-6f);
    if (tid == 0) atomicAdd(e_acc, rms);
    float inv = 1.f / rms;
    float4 wv = ((const float4*)nw)[tid];
    uint2 o;
    o.x = (unsigned)f2bf(v.x * wv.x * inv) | ((unsigned)f2bf(v.y * wv.y * inv) << 16);
    o.y = (unsigned)f2bf(v.z * wv.z * inv) | ((unsigned)f2bf(v.w * wv.w * inv) << 16);
    ((uint2*)xout_bf)[base] = o;
}

// ------- k_mod[z,t,e] = sum_d k_bf[b,t,1024+h*64+d] * rel[h,d,e] ---------
__global__ __launch_bounds__(256) void kmod_kernel(
    const unsigned short* __restrict__ qkv, const float* __restrict__ rel,
    unsigned short* __restrict__ kmod_bf)
{
    __shared__ float Rs[64 * 64];
    int z = blockIdx.y;
    int b = z >> 4, h = z & 15;
    int tid = threadIdx.x;
    const float4* r4 = (const float4*)(rel + (long long)h * 4096);
    float4* Rs4 = (float4*)Rs;
#pragma unroll
    for (int i = 0; i < 4; i++) Rs4[tid + 256 * i] = r4[tid + 256 * i];
    __syncthreads();
    int e = tid & 63, tl = tid >> 6;
    int t = blockIdx.x * 4 + tl;
    const unsigned short* krow = qkv + ((long long)(b * TT + t)) * QKV_LD + D + h * DH;
    float acc = 0.f;
#pragma unroll
    for (int d4 = 0; d4 < 16; d4++) {
        uint2 p = *(const uint2*)&krow[d4 * 4];
        acc += bf2f(p.x & 0xFFFFu) * Rs[(d4 * 4 + 0) * 64 + e];
        acc += bf2f(p.x >> 16)     * Rs[(d4 * 4 + 1) * 64 + e];
        acc += bf2f(p.y & 0xFFFFu) * Rs[(d4 * 4 + 2) * 64 + e];
        acc += bf2f(p.y >> 16)     * Rs[(d4 * 4 + 3) * 64 + e];
    }
    kmod_bf[(long long)z * (TT * DH) + t * 64 + e] = f2bf(acc);
}

// ---- vT[z][d][t] = qkv[b, t, 2048 + h*64 + d]  (64xTT per z, bf16) ------
__global__ __launch_bounds__(256) void vtrans_kernel(
    const unsigned short* __restrict__ qkv, unsigned short* __restrict__ vT)
{
    __shared__ unsigned short tile[64][68];
    int z = blockIdx.y, b = z >> 4, h = z & 15;
    int t0 = blockIdx.x * 64;
    int tid = threadIdx.x;
    int tr = tid >> 4;
    int dc = (tid & 15) * 4;
#pragma unroll
    for (int r = 0; r < 4; r++) {
        int t = tr + r * 16;
        uint2 p = *(const uint2*)&qkv[((long long)(b * TT + t0 + t)) * QKV_LD + 2 * D + h * DH + dc];
        tile[t][dc] = (unsigned short)(p.x & 0xFFFFu);
        tile[t][dc + 1] = (unsigned short)(p.x >> 16);
        tile[t][dc + 2] = (unsigned short)(p.y & 0xFFFFu);
        tile[t][dc + 3] = (unsigned short)(p.y >> 16);
    }
    __syncthreads();
#pragma unroll
    for (int r = 0; r < 4; r++) {
        int d = tr + r * 16;
        int t = (tid & 15) * 4;
        uint2 p;
        p.x = (unsigned)tile[t][d] | ((unsigned)tile[t + 1][d] << 16);
        p.y = (unsigned)tile[t + 2][d] | ((unsigned)tile[t + 3][d] << 16);
        *(uint2*)&vT[(long long)z * 64 * TT + (long long)d * TT + t0 + t] = p;
    }
}

// =======================================================================
// Fused flash-style attention (q read from merged qkv, stride QKV_LD).
// =======================================================================
__global__ __launch_bounds__(256, 2) void attn_fused_kernel(
    const unsigned short* __restrict__ qkv,   // [4096][3072] bf16
    const unsigned short* __restrict__ kmod,  // [32][2048][64] bf16
    const unsigned short* __restrict__ vT,    // [32][64][2048] bf16
    float* __restrict__ attn,                 // [32][2048][2048] fp32 out
    unsigned short* __restrict__ ctx)         // [4096][1024] bf16 out
{
    constexpr int QS_LD = 72;
    constexpr int PS_LD = 136;
    __shared__ __align__(16) unsigned short Qs[128 * QS_LD];
    __shared__ __align__(16) unsigned short Ks[128 * QS_LD];
    __shared__ __align__(16) unsigned short Ps[128 * PS_LD];
    __shared__ float sm_h[2][128];
    __shared__ float sl_h[2][128];

    // XCD swizzle over flat (z, qtile) grid: consecutive wgs share z (K/V)
    int nwg = gridDim.x * gridDim.y;
    int wg = blockIdx.y * gridDim.x + blockIdx.x;
    int swz = xcd_swz(wg, nwg);
    const int z = swz / (int)gridDim.x;
    const int q0 = (swz % (int)gridDim.x) * 128;
    const int b = z >> 4, h = z & 15;
    const int tid = threadIdx.x;
    const int lane = tid & 63;
    const int wave = tid >> 6;
    const int wr = wave >> 1, wc = wave & 1;
    const int lm = lane & 15, q4 = lane >> 4;
    const int kq = q4 * 8;

    {
        const unsigned short* qbase = qkv + ((long long)(b * TT + q0)) * QKV_LD + h * DH;
#pragma unroll
        for (int rr = 0; rr < 4; rr++) {
            int q = rr * 256 + tid;
            int row = q >> 3, seg = q & 7;
            short8 v = *(const short8*)(qbase + (long long)row * QKV_LD + seg * 8);
            *(short8*)&Qs[row * QS_LD + seg * 8] = v;
        }
    }

    const unsigned short* kz = kmod + (long long)z * (TT * DH);

    float m_loc[4][4], l_loc[4][4];
#pragma unroll
    for (int i = 0; i < 4; i++)
#pragma unroll
        for (int r = 0; r < 4; r++) { m_loc[i][r] = -FLT_MAX; l_loc[i][r] = 0.f; }

    // ---------------- pass 1: exact row max + exp-sum (online) ----------
    for (int kt = 0; kt < 16; kt++) {
        __syncthreads();
#pragma unroll
        for (int rr = 0; rr < 4; rr++) {
            int q = rr * 256 + tid;
            int row = q >> 3, seg = q & 7;
            short8 v = *(const short8*)(kz + (long long)(kt * 128 + row) * DH + seg * 8);
            *(short8*)&Ks[row * QS_LD + seg * 8] = v;
        }
        __syncthreads();
        f32x4 acc[4][4] = {};
#pragma unroll
        for (int ks = 0; ks < 2; ks++) {
            short8 af[4], bfk[4];
#pragma unroll
            for (int i = 0; i < 4; i++)
                af[i] = *(const short8*)&Qs[(wr * 64 + i * 16 + lm) * QS_LD + ks * 32 + kq];
#pragma unroll
            for (int j = 0; j < 4; j++)
                bfk[j] = *(const short8*)&Ks[(wc * 64 + j * 16 + lm) * QS_LD + ks * 32 + kq];
#pragma unroll
            for (int i = 0; i < 4; i++)
#pragma unroll
                for (int j = 0; j < 4; j++)
                    acc[i][j] = __builtin_amdgcn_mfma_f32_16x16x32_bf16(af[i], bfk[j], acc[i][j], 0, 0, 0);
        }
#pragma unroll
        for (int i = 0; i < 4; i++)
#pragma unroll
            for (int r = 0; r < 4; r++) {
                float v0 = acc[i][0][r] * 0.125f;
                float v1 = acc[i][1][r] * 0.125f;
                float v2 = acc[i][2][r] * 0.125f;
                float v3 = acc[i][3][r] * 0.125f;
                float tmax = fmaxf(fmaxf(v0, v1), fmaxf(v2, v3));
                float mo = m_loc[i][r];
                float mn = fmaxf(mo, tmax);
                l_loc[i][r] = l_loc[i][r] * __expf(mo - mn)
                            + __expf(v0 - mn) + __expf(v1 - mn)
                            + __expf(v2 - mn) + __expf(v3 - mn);
                m_loc[i][r] = mn;
            }
    }

#pragma unroll
    for (int off = 1; off <= 8; off <<= 1) {
#pragma unroll
        for (int i = 0; i < 4; i++)
#pragma unroll
            for (int r = 0; r < 4; r++) {
                float mo = __shfl_xor(m_loc[i][r], off);
                float lo = __shfl_xor(l_loc[i][r], off);
                float mn = fmaxf(m_loc[i][r], mo);
                l_loc[i][r] = l_loc[i][r] * __expf(m_loc[i][r] - mn) + lo * __expf(mo - mn);
                m_loc[i][r] = mn;
            }
    }
    if (lm == 0) {
#pragma unroll
        for (int i = 0; i < 4; i++)
#pragma unroll
            for (int r = 0; r < 4; r++) {
                int row = wr * 64 + i * 16 + q4 * 4 + r;
                sm_h[wc][row] = m_loc[i][r];
                sl_h[wc][row] = l_loc[i][r];
            }
    }
    __syncthreads();
    float Mf[4][4], Linv[4][4];
#pragma unroll
    for (int i = 0; i < 4; i++)
#pragma unroll
        for (int r = 0; r < 4; r++) {
            int row = wr * 64 + i * 16 + q4 * 4 + r;
            float m0 = sm_h[0][row], m1 = sm_h[1][row];
            float l0 = sl_h[0][row], l1 = sl_h[1][row];
            float mn = fmaxf(m0, m1);
            float L = l0 * __expf(m0 - mn) + l1 * __expf(m1 - mn);
            Mf[i][r] = mn;
            Linv[i][r] = 1.f / L;
        }

    // ---------------- pass 2: p -> attn (fp32, once) + PV ---------------
    const unsigned short* vz = vT + (long long)z * (64 * TT);
    float* az = attn + (long long)z * ((long long)TT * TT);
    f32x4 acc_o[4][2] = {};

    for (int kt = 0; kt < 16; kt++) {
        __syncthreads();
#pragma unroll
        for (int rr = 0; rr < 4; rr++) {
            int q = rr * 256 + tid;
            int row = q >> 3, seg = q & 7;
            short8 v = *(const short8*)(kz + (long long)(kt * 128 + row) * DH + seg * 8);
            *(short8*)&Ks[row * QS_LD + seg * 8] = v;
        }
        short8 bv[2][4];
#pragma unroll
        for (int j = 0; j < 2; j++)
#pragma unroll
            for (int ks = 0; ks < 4; ks++)
                bv[j][ks] = *(const short8*)(vz + (long long)(wc * 32 + j * 16 + lm) * TT
                                             + kt * 128 + ks * 32 + kq);
        __syncthreads();
        f32x4 acc[4][4] = {};
#pragma unroll
        for (int ks = 0; ks < 2; ks++) {
            short8 af[4], bfk[4];
#pragma unroll
            for (int i = 0; i < 4; i++)
                af[i] = *(const short8*)&Qs[(wr * 64 + i * 16 + lm) * QS_LD + ks * 32 + kq];
#pragma unroll
            for (int j = 0; j < 4; j++)
                bfk[j] = *(const short8*)&Ks[(wc * 64 + j * 16 + lm) * QS_LD + ks * 32 + kq];
#pragma unroll
            for (int i = 0; i < 4; i++)
#pragma unroll
                for (int j = 0; j < 4; j++)
                    acc[i][j] = __builtin_amdgcn_mfma_f32_16x16x32_bf16(af[i], bfk[j], acc[i][j], 0, 0, 0);
        }
#pragma unroll
        for (int i = 0; i < 4; i++)
#pragma unroll
            for (int r = 0; r < 4; r++) {
                int row = wr * 64 + i * 16 + q4 * 4 + r;
                float* arow = az + (long long)(q0 + row) * TT + kt * 128 + wc * 64 + lm;
#pragma unroll
                for (int j = 0; j < 4; j++) {
                    float p = __expf(acc[i][j][r] * 0.125f - Mf[i][r]) * Linv[i][r];
                    arow[j * 16] = p;
                    Ps[row * PS_LD + wc * 64 + j * 16 + lm] = f2bf(p);
                }
            }
        __syncthreads();
#pragma unroll
        for (int ks = 0; ks < 4; ks++) {
            short8 paf[4];
#pragma unroll
            for (int i = 0; i < 4; i++)
                paf[i] = *(const short8*)&Ps[(wr * 64 + i * 16 + lm) * PS_LD + ks * 32 + kq];
#pragma unroll
            for (int i = 0; i < 4; i++)
#pragma unroll
                for (int j = 0; j < 2; j++)
                    acc_o[i][j] = __builtin_amdgcn_mfma_f32_16x16x32_bf16(paf[i], bv[j][ks], acc_o[i][j], 0, 0, 0);
        }
    }

#pragma unroll
    for (int i = 0; i < 4; i++)
#pragma unroll
        for (int r = 0; r < 4; r++) {
            int row = wr * 64 + i * 16 + q4 * 4 + r;
            long long crow = ((long long)(b * TT + q0 + row)) * D + h * DH;
#pragma unroll
            for (int j = 0; j < 2; j++)
                ctx[crow + wc * 32 + j * 16 + lm] = f2bf(acc_o[i][j][r]);
        }
}

// --- h = sigmoid(g)*silu(u) in-place in merged [4096][8192] gu buffer ----
__global__ __launch_bounds__(256) void gateup_kernel(
    unsigned short* __restrict__ gu, long long n4)   // n4 = ROWS*DFF/4
{
    long long i = (long long)blockIdx.x * 256 + threadIdx.x;
    long long stride = (long long)gridDim.x * 256;
    uint2* gu2 = (uint2*)gu;
    for (; i < n4; i += stride) {
        long long row = i >> 10, c = i & 1023;       // DFF/4 = 1024 uint2/row-half
        uint2* gp = gu2 + row * 2048 + c;
        const uint2* up = gu2 + row * 2048 + 1024 + c;
        uint2 g = *gp;
        uint2 u = *up;
        float gv[4] = { bf2f(g.x & 0xFFFFu), bf2f(g.x >> 16), bf2f(g.y & 0xFFFFu), bf2f(g.y >> 16) };
        float uv[4] = { bf2f(u.x & 0xFFFFu), bf2f(u.x >> 16), bf2f(u.y & 0xFFFFu), bf2f(u.y >> 16) };
        unsigned short hh[4];
#pragma unroll
        for (int j = 0; j < 4; j++) {
            float r = (1.f / (1.f + __expf(-gv[j]))) * uv[j] * (1.f / (1.f + __expf(-uv[j])));
            hh[j] = f2bf(r);
        }
        uint2 o;
        o.x = (unsigned)hh[0] | ((unsigned)hh[1] << 16);
        o.y = (unsigned)hh[2] | ((unsigned)hh[3] << 16);
        *gp = o;
    }
}

// ---------------- finalize scalars ----------------
__global__ void finalize_kernel(const float* __restrict__ scal, float* __restrict__ out)
{
    out[OUT_SPARS] = scal[0] / (float)((double)ROWS * (double)MDICT);
    out[OUT_E1] = scal[1] / (float)ROWS;
    out[OUT_E2] = scal[2] / (float)ROWS;
}

extern "C" void kernel_launch(void* const* d_in, const int* in_sizes, int n_in,
                              void* d_out, int out_size, void* d_ws, size_t ws_size,
                              hipStream_t stream) {
    const float* x     = (const float*)d_in[0];
    const float* proto = (const float*)d_in[2];
    const float* fgw   = (const float*)d_in[3];
    const float* dictw = (const float*)d_in[4];
    const float* encw  = (const float*)d_in[5];
    const float* wq    = (const float*)d_in[6];
    const float* wk    = (const float*)d_in[7];
    const float* wv    = (const float*)d_in[8];
    const float* wo    = (const float*)d_in[9];
    const float* rel   = (const float*)d_in[10];
    const float* gatew = (const float*)d_in[11];
    const float* upw   = (const float*)d_in[12];
    const float* downw = (const float*)d_in[13];
    const float* n1w   = (const float*)d_in[14];
    const float* n2w   = (const float*)d_in[15];
    const float* bias  = (const float*)d_in[16];
    float* out = (float*)d_out;
    float* ws  = (float*)d_ws;

    // ---- ws arena (float offsets; bf16 buffers sized n/2 floats) ----
    float*          basisf  = ws + 0;                            // 4.19M fl (also xmid)
    unsigned short* qkv_bf  = (unsigned short*)(ws + 4194304);   // [4096][3072] bf16
    unsigned short* kmod_bf = (unsigned short*)(ws + 10485760);
    unsigned short* vT_bf   = (unsigned short*)(ws + 12582912);
    unsigned short* resid_bf= (unsigned short*)(ws + 14680064);  // also ctx_bf
    unsigned short* norm_bf = (unsigned short*)(ws + 16777216);  // normed / normed2
    unsigned short* encw_bf = (unsigned short*)(ws + 18874368);  // 8.39M fl
    unsigned short* gu_bf   = (unsigned short*)(ws + 18874368);  // [4096][8192] (16.78M fl, after enc done)
    unsigned short* wq_bf   = (unsigned short*)(ws + 35651584);  // wq|wk|wv contiguous
    unsigned short* wk_bf   = (unsigned short*)(ws + 36175872);
    unsigned short* wv_bf   = (unsigned short*)(ws + 36700160);
    unsigned short* wo_bf   = (unsigned short*)(ws + 37224448);
    unsigned short* gatew_bf= (unsigned short*)(ws + 37748736);  // gate|up contiguous
    unsigned short* upw_bf  = (unsigned short*)(ws + 39845888);
    unsigned short* downw_bf= (unsigned short*)(ws + 41943040);
    float*          tkv     = ws + 44040192;
    int*            tki     = (int*)(ws + 44072960);
    float*          scal    = ws + 44105728;
    unsigned short* ctx_bf  = resid_bf;
    float*          xmid    = basisf;

    float* fs   = out + OUT_FS;
    float* attn = out + OUT_ATTN;
    // candidate scratch lives in attn region (consumed before attn written)
    float* cand_v = attn;
    int*   cand_i = (int*)(attn + 4194304);

    hipMemsetAsync(scal, 0, 3 * sizeof(float), stream);

    // weight conversions (fp32 -> bf16)
    cvt_bf16_kernel<<<2048, 256, 0, stream>>>(encw, encw_bf, (long long)MDICT * D / 4);
    cvt_bf16_kernel<<<256, 256, 0, stream>>>(wq, wq_bf, (long long)D * D / 4);
    cvt_bf16_kernel<<<256, 256, 0, stream>>>(wk, wk_bf, (long long)D * D / 4);
    cvt_bf16_kernel<<<256, 256, 0, stream>>>(wv, wv_bf, (long long)D * D / 4);
    cvt_bf16_kernel<<<256, 256, 0, stream>>>(wo, wo_bf, (long long)D * D / 4);
    cvt_bf16_kernel<<<1024, 256, 0, stream>>>(gatew, gatew_bf, (long long)DFF * D / 4);
    cvt_bf16_kernel<<<1024, 256, 0, stream>>>(upw, upw_bf, (long long)DFF * D / 4);
    cvt_bf16_kernel<<<1024, 256, 0, stream>>>(downw, downw_bf, (long long)D * DFF / 4);

    family_kernel<<<ROWS, 64, 0, stream>>>(x, fgw, fs);
    basis_kernel<<<ROWS, 256, 0, stream>>>(x, fs, proto, basisf, resid_bf);
    // encoder GEMM with fused per-tile top-8 (coeffs never materialized)
    gemm_topk<<<dim3(128, 32, 1), 256, 0, stream>>>(resid_bf, encw_bf, cand_v, cand_i);
    topk_reduce_kernel<<<ROWS, 256, 0, stream>>>(cand_v, cand_i, tkv, tki, scal + 0);
    xrec_norm_kernel<<<ROWS, 256, 0, stream>>>(basisf, dictw, bias, n1w, tkv, tki, norm_bf, scal + 1);
    // merged QKV GEMM: [4096][3072] = normed @ [wq|wk|wv]^T
    gemm_mfma<128, 128, true><<<dim3(24, 32, 1), 256, 0, stream>>>(
        norm_bf, wq_bf, qkv_bf, nullptr, D, D, D, QKV_LD, 1.f);
    kmod_kernel<<<dim3(TT / 4, 32), 256, 0, stream>>>(qkv_bf, rel, kmod_bf);
    vtrans_kernel<<<dim3(TT / 64, 32), 256, 0, stream>>>(qkv_bf, vT_bf);
    // fused attention: scores + softmax + PV; attn written once (fp32)
    attn_fused_kernel<<<dim3(TT / 128, 32), 256, 0, stream>>>(
        qkv_bf, kmod_bf, vT_bf, attn, ctx_bf);
    // xmid = ctx @ wo^T + x  (fp32)
    gemm_mfma<128, 128, false><<<dim3(8, 32, 1), 256, 0, stream>>>(
        ctx_bf, wo_bf, xmid, x, D, D, D, D, 1.f);
    rmsnorm_kernel<<<ROWS, 256, 0, stream>>>(xmid, n2w, norm_bf, scal + 2);
    // merged gate|up GEMM: [4096][8192] = normed2 @ [gate|up]^T
    gemm_mfma<128, 128, true><<<dim3(64, 32, 1), 256, 0, stream>>>(
        norm_bf, gatew_bf, gu_bf, nullptr, D, D, D, 2 * DFF, 1.f);
    gateup_kernel<<<4096, 256, 0, stream>>>(gu_bf, (long long)ROWS * DFF / 4);
    // out_x = h @ down^T + xmid (fp32); h is gate half of gu (lda 8192)
    gemm_mfma<128, 128, false><<<dim3(8, 32, 1), 256, 0, stream>>>(
        gu_bf, downw_bf, out + OUT_X, xmid, DFF, 2 * DFF, DFF, D, 1.f);
    finalize_kernel<<<1, 1, 0, stream>>>(scal, out);
}